// Round 22
// baseline (447.084 us; speedup 1.0000x reference)
//
#include <hip/hip_runtime.h>
#include <stdint.h>

#define BB 8
#define CCH 64
#define NPB 4096
#define NPTS (BB*NPB)   // 32768
#define PPW 8           // points per wave in k_mlp2

typedef float  f32x2  __attribute__((ext_vector_type(2)));
typedef float  f32x4v __attribute__((ext_vector_type(4)));
typedef short  bf16x8 __attribute__((ext_vector_type(8)));
typedef unsigned short u16x8 __attribute__((ext_vector_type(8)));
typedef unsigned long long u64;
typedef unsigned int u32;

// round-to-nearest-even f32 -> bf16 bits (monotone for nonneg inputs)
__device__ __forceinline__ unsigned short f2bf(float x) {
    u32 u = __float_as_uint(x);
    u += 0x7FFFu + ((u >> 16) & 1u);
    return (unsigned short)(u >> 16);
}

// ---------------- K1: fused transpose + sq + bf16 cast (PASSING since R19) ----------------
__global__ void k_transpose(const float* __restrict__ x, float* __restrict__ xb,
                            unsigned short* __restrict__ xh, float* __restrict__ sq) {
    __shared__ float tile[64][65];
    int b  = blockIdx.y;
    int n0 = blockIdx.x * 64;
    int tx = threadIdx.x, ty = threadIdx.y;   // 64 x 8
    const float* xp = x + (size_t)b * CCH * NPB;
#pragma unroll
    for (int r = 0; r < 8; ++r) {
        int c = ty + r * 8;
        tile[c][tx] = xp[(size_t)c * NPB + n0 + tx];
    }
    __syncthreads();
    float* xbp = xb + ((size_t)b * NPB + n0) * CCH;
    unsigned short* xhp = xh + ((size_t)b * NPB + n0) * CCH;
    float* sqp = sq + (size_t)b * NPB + n0;
#pragma unroll
    for (int r = 0; r < 8; ++r) {
        int nn = ty + r * 8;
        float v = tile[tx][nn];
        xbp[(size_t)nn * CCH + tx] = v;
        xhp[(size_t)nn * CCH + tx] = f2bf(v);
        float s = v * v;
#pragma unroll
        for (int o = 32; o > 0; o >>= 1) s += __shfl_xor(s, o);
        if (tx == 0) sqp[nn] = s;
    }
}

// ---------------- K1d: fold + transpose weights to bf16 (PASSING) ----------------
__global__ void k_prepw(const float* __restrict__ W1, const float* __restrict__ W2,
                        unsigned short* __restrict__ W1t, unsigned short* __restrict__ W2t) {
    int t = blockIdx.x * 256 + threadIdx.x;     // 12288 threads
    if (t < 8192) {
        int o = t >> 7, k = t & 127;
        float v = (k < 64) ? (W1[k * 64 + o] - W1[(64 + k) * 64 + o]) : W1[k * 64 + o];
        W1t[o * 128 + k] = f2bf(v);
    } else if (t < 12288) {
        int u = t - 8192;
        int o = u >> 6, j = u & 63;
        W2t[o * 64 + j] = f2bf(W2[j * 64 + o]);
    }
}

// ---------------- K2: MFMA 64x64 distance tile -> bf16 dt (R21 body, PASSING) ----------------
__global__ __launch_bounds__(256) void k_gemm(const unsigned short* __restrict__ xh,
                                              const float* __restrict__ sq,
                                              unsigned short* __restrict__ dt,
                                              int b0) {
    __shared__ float dtile[64][68];
    int bl = blockIdx.y >> 6;                   // local batch in strip
    int b  = b0 + bl;                           // global batch (scalar)
    const unsigned short* xhB = xh + (size_t)b * NPB * CCH;
    const float* sqB = sq + (size_t)b * NPB;
    int l = threadIdx.x & 63;
    int w = threadIdx.x >> 6;
    int m0 = (blockIdx.y & 63) * 64;
    int n0 = blockIdx.x * 64;
    const unsigned short* ap = xhB + (size_t)(m0 + w * 16 + (l & 15)) * CCH + ((l >> 4) * 8);
    bf16x8 a0 = *(const bf16x8*)ap;
    bf16x8 a1 = *(const bf16x8*)(ap + 32);
    f32x4v z = {0.f, 0.f, 0.f, 0.f};
    f32x4v acc[4];
#pragma unroll
    for (int cg = 0; cg < 4; ++cg) {
        const unsigned short* bp = xhB + (size_t)(n0 + cg * 16 + (l & 15)) * CCH + ((l >> 4) * 8);
        bf16x8 b0v = *(const bf16x8*)bp;
        bf16x8 b1v = *(const bf16x8*)(bp + 32);
        acc[cg] = __builtin_amdgcn_mfma_f32_16x16x32_bf16(a0, b0v, z, 0, 0, 0);
        acc[cg] = __builtin_amdgcn_mfma_f32_16x16x32_bf16(a1, b1v, acc[cg], 0, 0, 0);
    }
    int rb = m0 + w * 16 + (l >> 4) * 4;
    float4 sr = *(const float4*)(sqB + rb);
    float sqr[4] = {sr.x, sr.y, sr.z, sr.w};
#pragma unroll
    for (int cg = 0; cg < 4; ++cg) {
        int cit = cg * 16 + (l & 15);
        float sc = sqB[n0 + cit];
#pragma unroll
        for (int j = 0; j < 4; ++j) {
            float v = fmaxf(fmaf(-2.f, acc[cg][j], sqr[j] + sc), 0.f);
            dtile[w * 16 + (l >> 4) * 4 + j][cit] = v;
        }
    }
    __syncthreads();
    int row = threadIdx.x >> 2;
    int c0  = (threadIdx.x & 3) * 16;
    const float4* dr = (const float4*)(&dtile[row][c0]);
    float4 v0 = dr[0], v1 = dr[1], v2 = dr[2], v3 = dr[3];
    u16x8 o0, o1;
    o0[0] = f2bf(v0.x); o0[1] = f2bf(v0.y); o0[2] = f2bf(v0.z); o0[3] = f2bf(v0.w);
    o0[4] = f2bf(v1.x); o0[5] = f2bf(v1.y); o0[6] = f2bf(v1.z); o0[7] = f2bf(v1.w);
    o1[0] = f2bf(v2.x); o1[1] = f2bf(v2.y); o1[2] = f2bf(v2.z); o1[3] = f2bf(v2.w);
    o1[4] = f2bf(v3.x); o1[5] = f2bf(v3.y); o1[6] = f2bf(v3.z); o1[7] = f2bf(v3.w);
    size_t base = ((size_t)(bl * NPB + m0 + row)) * NPB + n0 + c0;
    *(u16x8*)(dt + base)     = o0;
    *(u16x8*)(dt + base + 8) = o1;
}

// ---------------- K3: block-per-row threshold-select + exact refine -> idx ----------------
// Block = 256 thr = 4 waves; wave w owns cols [w*1024, w*1024+1024), 16 u16
// per lane (fits the natural 48-VGPR shape; R19-proven, no remat). Count via
// ballot+popcount (VALU+SALU, no shuffles); block combine via 4-entry LDS.
// Scatter strict/tie classes (R20/21-proven semantics) with per-wave bases;
// wave 0 refines (byte-identical fp32 math) + 64-lane bitonic sort.
__global__ __launch_bounds__(256, 1) void k_post(const unsigned short* __restrict__ dt,
                                                 const float* __restrict__ xb,
                                                 const float* __restrict__ sq,
                                                 int* __restrict__ idxo,
                                                 int b0) {
    __shared__ int cnts[4];
    __shared__ int wts[4], wtt[4];
    __shared__ u32 slots[64];
    int l  = threadIdx.x & 63;
    int w  = __builtin_amdgcn_readfirstlane(threadIdx.x >> 6);  // scalar wave id
    int rowl = blockIdx.x;                      // row within strip
    int bl   = rowl >> 12;
    int b    = b0 + bl;
    int row  = rowl & 4095;
    size_t rowg = (size_t)b * NPB + row;
    const float* xbB = xb + ((size_t)b << 12) * CCH;
    const float* sqB = sq + ((size_t)b << 12);

    // my 16 d~ values (cols w*1024 + l*16 .. +15)
    int cbase = w * 1024 + l * 16;
    u32 va[16];
    {
        const u16x8* dp = (const u16x8*)(dt + (size_t)rowl * NPB + cbase);
        u16x8 v0 = dp[0], v1 = dp[1];
#pragma unroll
        for (int e = 0; e < 8; ++e) { va[e] = (u32)v0[e]; va[8 + e] = (u32)v1[e]; }
    }
    // ---- block-global binary search: v* = min v with count(<=v) >= 48 ----
    u32 lo = 0, hi = 0x7FFFu;
#pragma unroll
    for (int it = 0; it < 15; ++it) {
        u32 mid = (lo + hi) >> 1;
        int c = 0;
#pragma unroll
        for (int i = 0; i < 16; ++i)
            c += (int)__popcll(__ballot(va[i] <= mid));
        if (l == 0) cnts[w] = c;
        __syncthreads();
        int ctot = cnts[0] + cnts[1] + cnts[2] + cnts[3];
        __syncthreads();
        bool ge = (ctot >= 48);
        lo = ge ? lo : (mid + 1);
        hi = ge ? mid : hi;
    }
    u32 vstar = hi;
    // ---- scatter: strict (<v*, total <=47) then ties (=v*, clamped to 64) ----
    int cs = 0, ct = 0;
#pragma unroll
    for (int i = 0; i < 16; ++i) {
        cs += (va[i] < vstar) ? 1 : 0;
        ct += (va[i] == vstar) ? 1 : 0;
    }
    int ps = cs, pt = ct;
#pragma unroll
    for (int d = 1; d < 64; d <<= 1) {
        int ts = __shfl_up(ps, d);
        int tt = __shfl_up(pt, d);
        if (l >= d) { ps += ts; pt += tt; }
    }
    if (l == 63) { wts[w] = ps; wtt[w] = pt; }
    if (threadIdx.x < 64) slots[threadIdx.x] = 0xFFFFFFFFu;
    __syncthreads();
    int sBase = 0, tBase = 0, totS = 0;
#pragma unroll
    for (int q = 0; q < 4; ++q) {
        totS += wts[q];
        if (q < w) { sBase += wts[q]; tBase += wtt[q]; }
    }
    int baseS = sBase + ps - cs;
    int baseT = totS + tBase + pt - ct;
    int ks = 0, kt = 0;
#pragma unroll
    for (int i = 0; i < 16; ++i) {
        u32 v = va[i];
        if (v < vstar) {
            slots[baseS + ks] = (v << 16) | (u32)(cbase + i);
            ks++;
        } else if (v == vstar) {
            int s = baseT + kt;
            if (s < 64) slots[s] = (v << 16) | (u32)(cbase + i);
            kt++;
        }
    }
    __syncthreads();
    if (w == 0) {
        // rr: wave-uniform row features -> s_load
        const float* xr = xbB + (size_t)row * CCH;
        float rr[64];
#pragma unroll
        for (int i = 0; i < 16; ++i) {
            float4 v = *(const float4*)(xr + i * 4);
            rr[4*i] = v.x; rr[4*i+1] = v.y; rr[4*i+2] = v.z; rr[4*i+3] = v.w;
        }
        u32 mk = slots[l];
        u64 key = ~0ULL;
        if (mk != 0xFFFFFFFFu) {
            int col = (int)(mk & 0xFFFFu);
            const float* xj = xbB + (size_t)col * CCH;
            float lod = 0.f, hid = 0.f;
#pragma unroll
            for (int q = 0; q < 8; ++q) {
                float4 v  = *(const float4*)(xj + q * 4);
                float4 wv = *(const float4*)(xj + 32 + q * 4);
                lod = fmaf(v.x,  rr[4*q+0], lod);
                lod = fmaf(v.y,  rr[4*q+1], lod);
                lod = fmaf(v.z,  rr[4*q+2], lod);
                lod = fmaf(v.w,  rr[4*q+3], lod);
                hid = fmaf(wv.x, rr[32+4*q+0], hid);
                hid = fmaf(wv.y, rr[32+4*q+1], hid);
                hid = fmaf(wv.z, rr[32+4*q+2], hid);
                hid = fmaf(wv.w, rr[32+4*q+3], hid);
            }
            float d = fmaf(-2.f, lod + hid, sqB[col]);
            u32 fb = __float_as_uint(d);
            fb ^= (fb >> 31) ? 0xFFFFFFFFu : 0x80000000u;   // monotonic
            key = ((u64)fb << 32) | (u32)col;
        }
        // 64-lane bitonic sort ascending on u64 keys (R19-proven)
#pragma unroll
        for (int kk = 2; kk <= 64; kk <<= 1) {
#pragma unroll
            for (int j = kk >> 1; j > 0; j >>= 1) {
                u64 p = (u64)__shfl_xor((long long)key, j);
                bool keep_min = (((l & kk) == 0) == ((l & j) == 0));
                bool plt = p < key;
                key = keep_min ? (plt ? p : key) : (plt ? key : p);
            }
        }
        if (l < 16) idxo[rowg * 16 + l] = (int)(key & 0xFFFFFFFFu);
    }
}

// ---------------- K4: MFMA edge-MLP + max over K (R18-R21 body, PASSING) ----------------
__global__ __launch_bounds__(256, 1) void k_mlp2(const unsigned short* __restrict__ xh,
                                                 const int* __restrict__ idx,
                                                 const unsigned short* __restrict__ W1t,
                                                 const unsigned short* __restrict__ W2t,
                                                 const float* __restrict__ b1,
                                                 const float* __restrict__ b2,
                                                 float* __restrict__ out) {
    __shared__ unsigned short h1l[4][16 * 72];
    int l   = threadIdx.x & 63;
    int wib = threadIdx.x >> 6;
    int e   = l & 15;
    int kg  = l >> 4;
    int wave = blockIdx.x * 4 + wib;            // 0..4095
    unsigned short* hl = h1l[wib];

    bf16x8 w1f[4][4];
#pragma unroll
    for (int nt = 0; nt < 4; ++nt)
#pragma unroll
        for (int s = 0; s < 4; ++s)
            w1f[nt][s] = *(const bf16x8*)(W1t + (size_t)(nt * 16 + e) * 128 + s * 32 + kg * 8);
    bf16x8 w2f[4][2];
#pragma unroll
    for (int nt = 0; nt < 4; ++nt)
#pragma unroll
        for (int s = 0; s < 2; ++s)
            w2f[nt][s] = *(const bf16x8*)(W2t + (size_t)(nt * 16 + e) * 64 + s * 32 + kg * 8);
    float b1v[4], b2v[4];
#pragma unroll
    for (int nt = 0; nt < 4; ++nt) { b1v[nt] = b1[nt * 16 + e]; b2v[nt] = b2[nt * 16 + e]; }

    int p0 = wave * PPW;
    int bb = p0 >> 12;
    int n0 = p0 & 4095;
    const unsigned short* xhB = xh + ((size_t)bb << 12) * CCH;
    f32x4v z = {0.f, 0.f, 0.f, 0.f};
    float mx[4][PPW];
#pragma unroll
    for (int nt = 0; nt < 4; ++nt)
#pragma unroll
        for (int pi = 0; pi < PPW; ++pi) mx[nt][pi] = 0.f;

#pragma unroll
    for (int pi = 0; pi < PPW; ++pi) {
        int n = n0 + pi;
        int je = idx[((size_t)(p0 + pi)) * 16 + e];
        bf16x8 a[4];
        a[0] = *(const bf16x8*)(xhB + (size_t)n * 64 + kg * 8);
        a[1] = *(const bf16x8*)(xhB + (size_t)n * 64 + 32 + kg * 8);
        a[2] = *(const bf16x8*)(xhB + (size_t)je * 64 + kg * 8);
        a[3] = *(const bf16x8*)(xhB + (size_t)je * 64 + 32 + kg * 8);
#pragma unroll
        for (int nt = 0; nt < 4; ++nt) {
            f32x4v acc = z;
#pragma unroll
            for (int s = 0; s < 4; ++s)
                acc = __builtin_amdgcn_mfma_f32_16x16x32_bf16(a[s], w1f[nt][s], acc, 0, 0, 0);
#pragma unroll
            for (int j = 0; j < 4; ++j) {
                float h = fmaxf(acc[j] + b1v[nt], 0.f);
                hl[(kg * 4 + j) * 72 + nt * 16 + e] = f2bf(h);
            }
        }
        bf16x8 a2[2];
        a2[0] = *(const bf16x8*)(hl + (size_t)e * 72 + kg * 8);
        a2[1] = *(const bf16x8*)(hl + (size_t)e * 72 + 32 + kg * 8);
#pragma unroll
        for (int nt = 0; nt < 4; ++nt) {
            f32x4v acc = z;
            acc = __builtin_amdgcn_mfma_f32_16x16x32_bf16(a2[0], w2f[nt][0], acc, 0, 0, 0);
            acc = __builtin_amdgcn_mfma_f32_16x16x32_bf16(a2[1], w2f[nt][1], acc, 0, 0, 0);
            float m4 = 0.f;
#pragma unroll
            for (int j = 0; j < 4; ++j)
                m4 = fmaxf(m4, fmaxf(acc[j] + b2v[nt], 0.f));
            mx[nt][pi] = m4;
        }
    }
#pragma unroll
    for (int nt = 0; nt < 4; ++nt)
#pragma unroll
        for (int pi = 0; pi < PPW; ++pi) {
            float v = mx[nt][pi];
            v = fmaxf(v, __shfl_xor(v, 16));
            v = fmaxf(v, __shfl_xor(v, 32));
            mx[nt][pi] = v;
        }
    if (kg == 0) {
#pragma unroll
        for (int nt = 0; nt < 4; ++nt) {
            float* op = out + ((size_t)bb * 64 + nt * 16 + e) * NPB + n0;
#pragma unroll
            for (int pi = 0; pi < PPW; ++pi) op[pi] = mx[nt][pi];
        }
    }
}

extern "C" void kernel_launch(void* const* d_in, const int* in_sizes, int n_in,
                              void* d_out, int out_size, void* d_ws, size_t ws_size,
                              hipStream_t stream) {
    const float* x  = (const float*)d_in[0];
    const float* W1 = (const float*)d_in[1];
    const float* b1 = (const float*)d_in[2];
    const float* W2 = (const float*)d_in[3];
    const float* b2 = (const float*)d_in[4];
    float* out = (float*)d_out;

    const size_t MB = 1024 * 1024;
    char* ws = (char*)d_ws;
    float*          xb  = (float*)(ws);                         // 0..8 MB
    unsigned short* xh  = (unsigned short*)(ws + 8 * MB);       // 8..12 MB
    float*          sq  = (float*)(ws + 12 * MB);               // 128 KB
    unsigned short* W1t = (unsigned short*)(ws + 12 * MB + 256 * 1024);   // 16 KB
    unsigned short* W2t = (unsigned short*)(ws + 12 * MB + 272 * 1024);   // 8 KB
    int*            idxb = (int*)(ws + 13 * MB);                // 2 MB
    unsigned short* dt  = (unsigned short*)(ws + 15 * MB);      // strip buffer
    const size_t dtPerBatch = (size_t)NPB * NPB * 2;            // 32 MiB

    hipLaunchKernelGGL(k_transpose, dim3(NPB / 64, BB), dim3(64, 8), 0, stream, x, xb, xh, sq);
    hipLaunchKernelGGL(k_prepw, dim3(48), dim3(256), 0, stream, W1, W2, W1t, W2t);

    int S = 0;
    for (int cand : {4, 2, 1}) {
        if (ws_size >= 15 * MB + (size_t)cand * dtPerBatch + 512 * 1024) { S = cand; break; }
    }
    if (S > 0) {
        for (int b0 = 0; b0 < BB; b0 += S) {
            hipLaunchKernelGGL(k_gemm, dim3(NPB / 64, 64 * S), dim3(256), 0, stream,
                               xh, sq, dt, b0);
            hipLaunchKernelGGL(k_post, dim3(S * NPB), dim3(256), 0, stream,
                               dt, xb, sq, idxb, b0);
        }
    }
    hipLaunchKernelGGL(k_mlp2, dim3(NPTS / PPW / 4), dim3(256), 0, stream,
                       xh, idxb, W1t, W2t, b1, b2, out);
}

// Round 23
// 322.049 us; speedup vs baseline: 1.3882x; 1.3882x over previous
//
#include <hip/hip_runtime.h>
#include <stdint.h>

#define BB 8
#define CCH 64
#define NPB 4096
#define NPTS (BB*NPB)   // 32768
#define PPW 8           // points per wave in k_mlp2

typedef float  f32x2  __attribute__((ext_vector_type(2)));
typedef float  f32x4v __attribute__((ext_vector_type(4)));
typedef short  bf16x8 __attribute__((ext_vector_type(8)));
typedef unsigned short u16x8 __attribute__((ext_vector_type(8)));
typedef unsigned long long u64;
typedef unsigned int u32;

// round-to-nearest-even f32 -> bf16 bits
__device__ __forceinline__ unsigned short f2bf(float x) {
    u32 u = __float_as_uint(x);
    u += 0x7FFFu + ((u >> 16) & 1u);
    return (unsigned short)(u >> 16);
}

// bitonic sort16 ascending (static indices, branchless) — proven since R6
template<typename T>
__device__ __forceinline__ void sort16(T* key) {
#pragma unroll
    for (int kk = 2; kk <= 16; kk <<= 1) {
#pragma unroll
        for (int j = kk >> 1; j > 0; j >>= 1) {
#pragma unroll
            for (int i = 0; i < 16; ++i) {
                int l = i ^ j;
                if (l > i) {
                    bool up = ((i & kk) == 0);
                    T a = key[i], c = key[l];
                    bool cond = up ? (c < a) : (a < c);
                    key[i] = cond ? c : a;
                    key[l] = cond ? a : c;
                }
            }
        }
    }
}

// keep 16 smallest of (list asc, key asc) -> list asc — proven since R6
template<typename T>
__device__ __forceinline__ void merge16(T* list, const T* key) {
    T m[16];
#pragma unroll
    for (int i = 0; i < 16; ++i) {
        T a = list[i], c = key[15 - i];
        m[i] = (c < a) ? c : a;
    }
#pragma unroll
    for (int j = 8; j > 0; j >>= 1) {
#pragma unroll
        for (int i = 0; i < 16; ++i) {
            if ((i & j) == 0) {
                T a = m[i], c = m[i + j];
                bool cond = c < a;
                m[i]     = cond ? c : a;
                m[i + j] = cond ? a : c;
            }
        }
    }
#pragma unroll
    for (int i = 0; i < 16; ++i) list[i] = m[i];
}

// ---------------- K1: fused transpose + sq + bf16 cast (R19 body, PASSING) ----------------
__global__ void k_transpose(const float* __restrict__ x, float* __restrict__ xb,
                            unsigned short* __restrict__ xh, float* __restrict__ sq) {
    __shared__ float tile[64][65];
    int b  = blockIdx.y;
    int n0 = blockIdx.x * 64;
    int tx = threadIdx.x, ty = threadIdx.y;   // 64 x 8
    const float* xp = x + (size_t)b * CCH * NPB;
#pragma unroll
    for (int r = 0; r < 8; ++r) {
        int c = ty + r * 8;
        tile[c][tx] = xp[(size_t)c * NPB + n0 + tx];
    }
    __syncthreads();
    float* xbp = xb + ((size_t)b * NPB + n0) * CCH;
    unsigned short* xhp = xh + ((size_t)b * NPB + n0) * CCH;
    float* sqp = sq + (size_t)b * NPB + n0;
#pragma unroll
    for (int r = 0; r < 8; ++r) {
        int nn = ty + r * 8;
        float v = tile[tx][nn];
        xbp[(size_t)nn * CCH + tx] = v;
        xhp[(size_t)nn * CCH + tx] = f2bf(v);
        float s = v * v;
#pragma unroll
        for (int o = 32; o > 0; o >>= 1) s += __shfl_xor(s, o);
        if (tx == 0) sqp[nn] = s;
    }
}

// ---------------- K1d: fold + transpose weights to bf16 (PASSING) ----------------
__global__ void k_prepw(const float* __restrict__ W1, const float* __restrict__ W2,
                        unsigned short* __restrict__ W1t, unsigned short* __restrict__ W2t) {
    int t = blockIdx.x * 256 + threadIdx.x;     // 12288 threads
    if (t < 8192) {
        int o = t >> 7, k = t & 127;
        float v = (k < 64) ? (W1[k * 64 + o] - W1[(64 + k) * 64 + o]) : W1[k * 64 + o];
        W1t[o * 128 + k] = f2bf(v);
    } else if (t < 12288) {
        int u = t - 8192;
        int o = u >> 6, j = u & 63;
        W2t[o * 64 + j] = f2bf(W2[j * 64 + o]);
    }
}

// ---------------- K2: MFMA 64x64 distance tile + fused per-row block top-16 ----------------
// R19 body (PASSING) with phase 3 split in two stages: stage A merges chunk
// pairs (0,1) and (2,3) on 128 threads (2 per row, disjoint llist regions);
// stage B does the single final merge on 64 threads. Serial merge depth 3->2.
// Selection semantics identical: top16(block) = merge(top16(01), top16(23)).
__global__ __launch_bounds__(256) void k_gemm(const unsigned short* __restrict__ xh,
                                              const float* __restrict__ sq,
                                              u32* __restrict__ cand) {
    __shared__ float dtile[64][65];
    __shared__ u32 llist[64][65];
    int b = blockIdx.y >> 6;                    // scalar batch
    const unsigned short* xhB = xh + (size_t)b * NPB * CCH;
    const float* sqB = sq + (size_t)b * NPB;
    u32* candB = cand + (size_t)b * 64 * NPB * 16;
    int l = threadIdx.x & 63;
    int w = threadIdx.x >> 6;
    int m0 = (blockIdx.y & 63) * 64;
    int n0 = blockIdx.x * 64;
    const unsigned short* ap = xhB + (size_t)(m0 + w * 16 + (l & 15)) * CCH + ((l >> 4) * 8);
    bf16x8 a0 = *(const bf16x8*)ap;
    bf16x8 a1 = *(const bf16x8*)(ap + 32);
    f32x4v z = {0.f, 0.f, 0.f, 0.f};
    f32x4v acc[4];
#pragma unroll
    for (int cg = 0; cg < 4; ++cg) {
        const unsigned short* bp = xhB + (size_t)(n0 + cg * 16 + (l & 15)) * CCH + ((l >> 4) * 8);
        bf16x8 b0 = *(const bf16x8*)bp;
        bf16x8 b1 = *(const bf16x8*)(bp + 32);
        acc[cg] = __builtin_amdgcn_mfma_f32_16x16x32_bf16(a0, b0, z, 0, 0, 0);
        acc[cg] = __builtin_amdgcn_mfma_f32_16x16x32_bf16(a1, b1, acc[cg], 0, 0, 0);
    }
    int rb = m0 + w * 16 + (l >> 4) * 4;
    float4 sr = *(const float4*)(sqB + rb);
    float sqr[4] = {sr.x, sr.y, sr.z, sr.w};
#pragma unroll
    for (int cg = 0; cg < 4; ++cg) {
        int cit = cg * 16 + (l & 15);
        float sc = sqB[n0 + cit];
#pragma unroll
        for (int j = 0; j < 4; ++j) {
            float v = fmaxf(fmaf(-2.f, acc[cg][j], sqr[j] + sc), 0.f);
            dtile[w * 16 + (l >> 4) * 4 + j][cit] = v;
        }
    }
    __syncthreads();
    // phase 2: wave w sorts chunk w for all 64 rows (lane = row)
    {
        int row = l, ch = w;
        u32 key[16];
#pragma unroll
        for (int e = 0; e < 16; ++e) {
            float v = dtile[row][ch * 16 + e];
            key[e] = ((u32)f2bf(v) << 16) | (u32)(n0 + ch * 16 + e);
        }
        sort16(key);
#pragma unroll
        for (int i = 0; i < 16; ++i) llist[row][ch * 16 + i] = key[i];
    }
    __syncthreads();
    // phase 3a: 128 threads (2 per row): merge chunks (0,1) and (2,3)
    if (threadIdx.x < 128) {
        int r2 = threadIdx.x & 63;
        int hf = threadIdx.x >> 6;              // 0 or 1 -> llist regions [0..31] / [32..63]
        u32 a[16], c[16];
#pragma unroll
        for (int i = 0; i < 16; ++i) a[i] = llist[r2][hf * 32 + i];
#pragma unroll
        for (int i = 0; i < 16; ++i) c[i] = llist[r2][hf * 32 + 16 + i];
        merge16(a, c);
#pragma unroll
        for (int i = 0; i < 16; ++i) llist[r2][hf * 32 + i] = a[i];
    }
    __syncthreads();
    // phase 3b: 64 threads: final merge -> cand
    if (threadIdx.x < 64) {
        int r2 = threadIdx.x;
        u32 list[16], tmp[16];
#pragma unroll
        for (int i = 0; i < 16; ++i) list[i] = llist[r2][i];
#pragma unroll
        for (int i = 0; i < 16; ++i) tmp[i] = llist[r2][32 + i];
        merge16(list, tmp);
        u32* cp = candB + ((size_t)blockIdx.x * NPB + (m0 + r2)) * 16;
#pragma unroll
        for (int i = 0; i < 16; ++i) cp[i] = list[i];
    }
}

// ---------------- K3: threshold-select + exact fp32 refine -> idx (R19 body, PASSING) ----------------
__global__ __launch_bounds__(256, 1) void k_post(const u32* __restrict__ cand,
                                                 const float* __restrict__ xb,
                                                 const float* __restrict__ sq,
                                                 int* __restrict__ idxo) {
    __shared__ u32 slots[4][64];
    int l  = threadIdx.x & 63;
    int rl = __builtin_amdgcn_readfirstlane(threadIdx.x >> 6);
    int rowg = blockIdx.x * 4 + rl;             // scalar global row
    int b    = rowg >> 12;                      // scalar batch
    int row  = rowg & 4095;
    const float* xbB = xb + ((size_t)b << 12) * CCH;
    const float* sqB = sq + ((size_t)b << 12);
    const u32* candB = cand + (size_t)b * 64 * NPB * 16;
    const float* xr = xbB + (size_t)row * CCH;  // uniform -> s_load
    float rr[64];
#pragma unroll
    for (int i = 0; i < 16; ++i) {
        float4 v = *(const float4*)(xr + i * 4);
        rr[4*i] = v.x; rr[4*i+1] = v.y; rr[4*i+2] = v.z; rr[4*i+3] = v.w;
    }
    u32 karr[16];
    {
        const uint4* cp = (const uint4*)(candB + ((size_t)l * NPB + row) * 16);
#pragma unroll
        for (int i = 0; i < 4; ++i) {
            uint4 v = cp[i];
            karr[4*i] = v.x; karr[4*i+1] = v.y; karr[4*i+2] = v.z; karr[4*i+3] = v.w;
        }
    }
    // ---- binary search on 16-bit bf16 value for v* (count >= 48) ----
    u32 lo = 0, hi = 0xFFFFu;
#pragma unroll
    for (int it = 0; it < 16; ++it) {
        u32 mid = (lo + hi) >> 1;
        int c = 0;
#pragma unroll
        for (int i = 0; i < 16; ++i) c += ((karr[i] >> 16) <= mid) ? 1 : 0;
#pragma unroll
        for (int o = 32; o > 0; o >>= 1) c += __shfl_xor(c, o);
        bool ge = (c >= 48);
        lo = ge ? lo : (mid + 1);
        hi = ge ? mid : hi;
    }
    u32 vstar = hi;
    // ---- scatter survivors (val <= v*) into <=64 LDS slots ----
    int cnt = 0;
#pragma unroll
    for (int i = 0; i < 16; ++i) cnt += ((karr[i] >> 16) <= vstar) ? 1 : 0;
    int pre = cnt;
#pragma unroll
    for (int d = 1; d < 64; d <<= 1) {
        int t = __shfl_up(pre, d);
        if (l >= d) pre += t;
    }
    int base = pre - cnt;
    u32* sl = slots[rl];                        // wave-private row
    sl[l] = 0xFFFFFFFFu;                        // in-wave DS order: init first
#pragma unroll
    for (int i = 0; i < 16; ++i) {
        if (i < cnt) {
            int s = base + i;
            if (s < 64) sl[s] = karr[i];
        }
    }
    u32 mk = sl[l];                             // wave-local, lgkmcnt-ordered
    // ---- exact fp32 distance for my survivor (byte-identical math) ----
    u64 key = ~0ULL;
    if (mk != 0xFFFFFFFFu) {
        int col = (int)(mk & 0xFFFFu);
        const float* xj = xbB + (size_t)col * CCH;
        float lod = 0.f, hid = 0.f;
#pragma unroll
        for (int q = 0; q < 8; ++q) {
            float4 v  = *(const float4*)(xj + q * 4);
            float4 wv = *(const float4*)(xj + 32 + q * 4);
            lod = fmaf(v.x,  rr[4*q+0], lod);
            lod = fmaf(v.y,  rr[4*q+1], lod);
            lod = fmaf(v.z,  rr[4*q+2], lod);
            lod = fmaf(v.w,  rr[4*q+3], lod);
            hid = fmaf(wv.x, rr[32+4*q+0], hid);
            hid = fmaf(wv.y, rr[32+4*q+1], hid);
            hid = fmaf(wv.z, rr[32+4*q+2], hid);
            hid = fmaf(wv.w, rr[32+4*q+3], hid);
        }
        float d = fmaf(-2.f, lod + hid, sqB[col]);
        u32 fb = __float_as_uint(d);
        fb ^= (fb >> 31) ? 0xFFFFFFFFu : 0x80000000u;   // monotonic
        key = ((u64)fb << 32) | (u32)col;
    }
    // ---- 64-lane bitonic sort ascending on u64 keys ----
#pragma unroll
    for (int kk = 2; kk <= 64; kk <<= 1) {
#pragma unroll
        for (int j = kk >> 1; j > 0; j >>= 1) {
            u64 p = (u64)__shfl_xor((long long)key, j);
            bool keep_min = (((l & kk) == 0) == ((l & j) == 0));
            bool plt = p < key;
            key = keep_min ? (plt ? p : key) : (plt ? key : p);
        }
    }
    if (l < 16) idxo[(size_t)rowg * 16 + l] = (int)(key & 0xFFFFFFFFu);
}

// ---------------- K4: MFMA edge-MLP + max over K (R18/R19 body, PASSING) ----------------
__global__ __launch_bounds__(256, 1) void k_mlp2(const unsigned short* __restrict__ xh,
                                                 const int* __restrict__ idx,
                                                 const unsigned short* __restrict__ W1t,
                                                 const unsigned short* __restrict__ W2t,
                                                 const float* __restrict__ b1,
                                                 const float* __restrict__ b2,
                                                 float* __restrict__ out) {
    __shared__ unsigned short h1l[4][16 * 72];
    int l   = threadIdx.x & 63;
    int wib = threadIdx.x >> 6;
    int e   = l & 15;
    int kg  = l >> 4;
    int wave = blockIdx.x * 4 + wib;            // 0..4095
    unsigned short* hl = h1l[wib];

    bf16x8 w1f[4][4];
#pragma unroll
    for (int nt = 0; nt < 4; ++nt)
#pragma unroll
        for (int s = 0; s < 4; ++s)
            w1f[nt][s] = *(const bf16x8*)(W1t + (size_t)(nt * 16 + e) * 128 + s * 32 + kg * 8);
    bf16x8 w2f[4][2];
#pragma unroll
    for (int nt = 0; nt < 4; ++nt)
#pragma unroll
        for (int s = 0; s < 2; ++s)
            w2f[nt][s] = *(const bf16x8*)(W2t + (size_t)(nt * 16 + e) * 64 + s * 32 + kg * 8);
    float b1v[4], b2v[4];
#pragma unroll
    for (int nt = 0; nt < 4; ++nt) { b1v[nt] = b1[nt * 16 + e]; b2v[nt] = b2[nt * 16 + e]; }

    int p0 = wave * PPW;
    int bb = p0 >> 12;
    int n0 = p0 & 4095;
    const unsigned short* xhB = xh + ((size_t)bb << 12) * CCH;
    f32x4v z = {0.f, 0.f, 0.f, 0.f};
    float mx[4][PPW];
#pragma unroll
    for (int nt = 0; nt < 4; ++nt)
#pragma unroll
        for (int pi = 0; pi < PPW; ++pi) mx[nt][pi] = 0.f;

#pragma unroll
    for (int pi = 0; pi < PPW; ++pi) {
        int n = n0 + pi;
        int je = idx[((size_t)(p0 + pi)) * 16 + e];
        bf16x8 a[4];
        a[0] = *(const bf16x8*)(xhB + (size_t)n * 64 + kg * 8);
        a[1] = *(const bf16x8*)(xhB + (size_t)n * 64 + 32 + kg * 8);
        a[2] = *(const bf16x8*)(xhB + (size_t)je * 64 + kg * 8);
        a[3] = *(const bf16x8*)(xhB + (size_t)je * 64 + 32 + kg * 8);
#pragma unroll
        for (int nt = 0; nt < 4; ++nt) {
            f32x4v acc = z;
#pragma unroll
            for (int s = 0; s < 4; ++s)
                acc = __builtin_amdgcn_mfma_f32_16x16x32_bf16(a[s], w1f[nt][s], acc, 0, 0, 0);
#pragma unroll
            for (int j = 0; j < 4; ++j) {
                float h = fmaxf(acc[j] + b1v[nt], 0.f);
                hl[(kg * 4 + j) * 72 + nt * 16 + e] = f2bf(h);
            }
        }
        bf16x8 a2[2];
        a2[0] = *(const bf16x8*)(hl + (size_t)e * 72 + kg * 8);
        a2[1] = *(const bf16x8*)(hl + (size_t)e * 72 + 32 + kg * 8);
#pragma unroll
        for (int nt = 0; nt < 4; ++nt) {
            f32x4v acc = z;
            acc = __builtin_amdgcn_mfma_f32_16x16x32_bf16(a2[0], w2f[nt][0], acc, 0, 0, 0);
            acc = __builtin_amdgcn_mfma_f32_16x16x32_bf16(a2[1], w2f[nt][1], acc, 0, 0, 0);
            float m4 = 0.f;
#pragma unroll
            for (int j = 0; j < 4; ++j)
                m4 = fmaxf(m4, fmaxf(acc[j] + b2v[nt], 0.f));
            mx[nt][pi] = m4;
        }
    }
#pragma unroll
    for (int nt = 0; nt < 4; ++nt)
#pragma unroll
        for (int pi = 0; pi < PPW; ++pi) {
            float v = mx[nt][pi];
            v = fmaxf(v, __shfl_xor(v, 16));
            v = fmaxf(v, __shfl_xor(v, 32));
            mx[nt][pi] = v;
        }
    if (kg == 0) {
#pragma unroll
        for (int nt = 0; nt < 4; ++nt) {
            float* op = out + ((size_t)bb * 64 + nt * 16 + e) * NPB + n0;
#pragma unroll
            for (int pi = 0; pi < PPW; ++pi) op[pi] = mx[nt][pi];
        }
    }
}

extern "C" void kernel_launch(void* const* d_in, const int* in_sizes, int n_in,
                              void* d_out, int out_size, void* d_ws, size_t ws_size,
                              hipStream_t stream) {
    const float* x  = (const float*)d_in[0];
    const float* W1 = (const float*)d_in[1];
    const float* b1 = (const float*)d_in[2];
    const float* W2 = (const float*)d_in[3];
    const float* b2 = (const float*)d_in[4];
    float* out = (float*)d_out;

    const size_t MB = 1024 * 1024;
    char* ws = (char*)d_ws;
    float*          xb  = (float*)(ws);                         // 8 MB
    unsigned short* xh  = (unsigned short*)(ws + 8 * MB);       // 4 MB
    float*          sq  = (float*)(ws + 12 * MB);               // 128 KB
    unsigned short* W1t = (unsigned short*)(ws + 12 * MB + 256 * 1024);   // 16 KB
    unsigned short* W2t = (unsigned short*)(ws + 12 * MB + 272 * 1024);   // 8 KB
    u32*            cand = (u32*)(ws + 13 * MB);
    size_t candAll = (size_t)BB * 64 * NPB * 16 * 4;            // 128 MiB
    size_t needF = 13 * MB + candAll + (size_t)NPTS * 16 * 4;

    hipLaunchKernelGGL(k_transpose, dim3(NPB / 64, BB), dim3(64, 8), 0, stream, x, xb, xh, sq);
    hipLaunchKernelGGL(k_prepw, dim3(48), dim3(256), 0, stream, W1, W2, W1t, W2t);

    if (ws_size >= needF + MB) {
        int* idxb = (int*)(ws + 13 * MB + candAll);
        hipLaunchKernelGGL(k_gemm, dim3(NPB / 64, 64 * BB), dim3(256), 0, stream,
                           xh, sq, cand);
        hipLaunchKernelGGL(k_post, dim3(NPTS / 4), dim3(256), 0, stream,
                           cand, xb, sq, idxb);
        hipLaunchKernelGGL(k_mlp2, dim3(NPTS / PPW / 4), dim3(256), 0, stream,
                           xh, idxb, W1t, W2t, b1, b2, out);
    } else {
        // fallback: per-batch loop (b=0 inside kernels via grid y=64); cand = 16 MiB
        int* idxb = (int*)(ws + 30 * MB);
        for (int b = 0; b < BB; ++b) {
            const unsigned short* xhB = xh + (size_t)b * NPB * CCH;
            const float* xbB = xb + (size_t)b * NPB * CCH;
            const float* sqB = sq + (size_t)b * NPB;
            hipLaunchKernelGGL(k_gemm, dim3(NPB / 64, 64), dim3(256), 0, stream,
                               xhB, sqB, cand);
            hipLaunchKernelGGL(k_post, dim3(NPB / 4), dim3(256), 0, stream,
                               cand, xbB, sqB, idxb + (size_t)b * NPB * 16);
        }
        hipLaunchKernelGGL(k_mlp2, dim3(NPTS / PPW / 4), dim3(256), 0, stream,
                           xh, idxb, W1t, W2t, b1, b2, out);
    }
}